// Round 1
// baseline (2372.405 us; speedup 1.0000x reference)
//
#include <hip/hip_runtime.h>
#include <hip/hip_bf16.h>

#define N_NODES 50000
#define E_EDGES 300000
#define NGRAPH 64
#define KTOT 16512   // 1024*16 kf  + 128 pad chunk (first 16 carry b2)
#define KC 128
#define NCHUNK 129
#define LNEPS 1e-5f

typedef __bf16 bf16x8 __attribute__((ext_vector_type(8)));
typedef float floatx4 __attribute__((ext_vector_type(4)));

__device__ __forceinline__ void async_load16(const void* g, void* l) {
  __builtin_amdgcn_global_load_lds(
      (__attribute__((address_space(1))) void*)g,
      (__attribute__((address_space(3))) void*)l, 16, 0, 0);
}

__device__ __forceinline__ unsigned fkey(float f) {
  unsigned u = __float_as_uint(f);
  return (u & 0x80000000u) ? ~u : (u | 0x80000000u);
}
__device__ __forceinline__ float fdec(unsigned k) {
  unsigned u = (k & 0x80000000u) ? (k & 0x7fffffffu) : ~k;
  return __uint_as_float(u);
}

// ---------------- prep: build Tt[h][kf] bf16 and W1t[k][8] ----------------
__global__ void k_prep(const float* __restrict__ w2, const float* __restrict__ b2,
                       const float* __restrict__ w1, __bf16* __restrict__ Tt,
                       float* __restrict__ W1t) {
  int idx = blockIdx.x * 256 + threadIdx.x;
  const int TT_E = 64 * KTOT;
  if (idx < TT_E) {
    int h = idx / KTOT;
    int kf = idx - h * KTOT;
    float v = 0.f;
    if (kf < 16384) {
      int k = kf >> 4, f = kf & 15;
      v = w2[k * 1024 + f * 64 + h];
    } else if (kf < 16400) {
      int f = kf - 16384;
      v = b2[f * 64 + h];
    }
    Tt[idx] = (__bf16)v;
  } else {
    int i2 = idx - TT_E;
    if (i2 < 8192) {
      int k = i2 >> 3, j = i2 & 7;
      W1t[i2] = w1[j * 1024 + k];
    }
  }
}

__global__ void k_deg(const int* __restrict__ ei, float* __restrict__ deg) {
  int e = blockIdx.x * 256 + threadIdx.x;
  if (e < E_EDGES) atomicAdd(&deg[ei[E_EDGES + e]], 1.0f);
}

// ---------------- NNConv fused MFMA GEMM ----------------
// C[e,h] = sum_kf Z[e,kf]*T[kf,h], Z[e,k*16+f]=r[e,k]*x[src_e,f]
__global__ __launch_bounds__(256, 2)
void k_nnconv(const float* __restrict__ x, const int* __restrict__ ei,
              const float* __restrict__ ea, const float* __restrict__ W1t,
              const float* __restrict__ b1, const __bf16* __restrict__ Tt,
              float* __restrict__ agg) {
  __shared__ __align__(16) __bf16 sB[2][64 * KC];  // 2 x 16KB, xor-swizzled rows
  __shared__ float sR[2][256 * 9];                 // r values, row pad 9
  __shared__ int sSrc[256];
  __shared__ int sDst[256];

  const int tid = threadIdx.x;
  const int wv = tid >> 6;
  const int lane = tid & 63;
  const int l15 = lane & 15;
  const int quad = lane >> 4;
  const int base = blockIdx.x * 256;

  int e = base + tid;
  bool valid = e < E_EDGES;
  sSrc[tid] = valid ? ei[e] : 0;
  sDst[tid] = valid ? ei[E_EDGES + e] : -1;

  float eaw[8];
  {
    const float4* p = (const float4*)(ea + (size_t)(valid ? e : 0) * 8);
    float4 a0 = p[0], a1 = p[1];
    eaw[0] = a0.x; eaw[1] = a0.y; eaw[2] = a0.z; eaw[3] = a0.w;
    eaw[4] = a1.x; eaw[5] = a1.y; eaw[6] = a1.z; eaw[7] = a1.w;
  }
  __syncthreads();

  // persistent x fragments: lane m=l15 of M-block mb, f = f0..f0+7
  const int f0 = (quad & 1) * 8;
  float xf[4][8];
#pragma unroll
  for (int mb = 0; mb < 4; ++mb) {
    int el = wv * 64 + mb * 16 + l15;
    const float4* px = (const float4*)(x + (size_t)sSrc[el] * 16 + f0);
    float4 v0 = px[0], v1 = px[1];
    xf[mb][0] = v0.x; xf[mb][1] = v0.y; xf[mb][2] = v0.z; xf[mb][3] = v0.w;
    xf[mb][4] = v1.x; xf[mb][5] = v1.y; xf[mb][6] = v1.z; xf[mb][7] = v1.w;
  }

  auto stage = [&](int buf, int c) {
    // B tile: 64 rows(h) x 128 kf bf16, 16B chunks xor-swizzled within rows
#pragma unroll
    for (int it = 0; it < 4; ++it) {
      int q = it * 256 + tid;
      int h = q >> 4, sc = q & 15;
      int cc = sc ^ (h & 15);
      async_load16(Tt + (size_t)h * KTOT + c * KC + cc * 8, &sB[buf][q * 8]);
    }
    // r values for k = c*8 .. c*8+7 (this thread's own edge)
#pragma unroll
    for (int kk = 0; kk < 8; ++kk) {
      int k = c * 8 + kk;
      float v;
      if (k < 1024) {
        const float4* w = (const float4*)(W1t + k * 8);
        float4 w0 = w[0], w1v = w[1];
        v = b1[k];
        v += eaw[0] * w0.x + eaw[1] * w0.y + eaw[2] * w0.z + eaw[3] * w0.w;
        v += eaw[4] * w1v.x + eaw[5] * w1v.y + eaw[6] * w1v.z + eaw[7] * w1v.w;
        v = fmaxf(v, 0.f);
      } else {
        v = (k == 1024) ? 1.0f : 0.0f;  // b2 row
      }
      if (!valid) v = 0.f;
      sR[buf][tid * 9 + kk] = v;
    }
  };

  floatx4 acc[4][4];
#pragma unroll
  for (int mb = 0; mb < 4; ++mb)
#pragma unroll
    for (int nb = 0; nb < 4; ++nb) acc[mb][nb] = floatx4{0.f, 0.f, 0.f, 0.f};

  stage(0, 0);
  int buf = 0;
  for (int c = 0; c < NCHUNK; ++c) {
    __syncthreads();
    if (c + 1 < NCHUNK) stage(buf ^ 1, c + 1);
#pragma unroll
    for (int ks = 0; ks < 4; ++ks) {
      bf16x8 bfr[4];
#pragma unroll
      for (int nb = 0; nb < 4; ++nb) {
        int h = nb * 16 + l15;
        int cc = (ks * 4 + quad) ^ l15;
        bfr[nb] = *(const bf16x8*)&sB[buf][h * KC + cc * 8];
      }
      int kl = ks * 2 + (quad >> 1);
#pragma unroll
      for (int mb = 0; mb < 4; ++mb) {
        int el = wv * 64 + mb * 16 + l15;
        float rv = sR[buf][el * 9 + kl];
        bf16x8 af;
#pragma unroll
        for (int j = 0; j < 8; ++j) af[j] = (__bf16)(rv * xf[mb][j]);
#pragma unroll
        for (int nb = 0; nb < 4; ++nb)
          acc[mb][nb] = __builtin_amdgcn_mfma_f32_16x16x32_bf16(af, bfr[nb], acc[mb][nb], 0, 0, 0);
      }
    }
    buf ^= 1;
  }

  // epilogue: scatter msg to agg[dst]  (C layout: row=quad*4+reg, col=l15)
#pragma unroll
  for (int mb = 0; mb < 4; ++mb) {
    int el = wv * 64 + mb * 16 + quad * 4;
#pragma unroll
    for (int reg = 0; reg < 4; ++reg) {
      int dd = sDst[el + reg];
      if (dd >= 0) {
#pragma unroll
        for (int nb = 0; nb < 4; ++nb)
          atomicAdd(&agg[(size_t)dd * 64 + nb * 16 + l15], acc[mb][nb][reg]);
      }
    }
  }
}

// ---------------- h = relu(x@rootw + agg/deg + b); LN1 stats ----------------
__global__ void k_root(const float* __restrict__ x, const float* __restrict__ rootw,
                       const float* __restrict__ conv1b, const float* __restrict__ agg,
                       const float* __restrict__ deg, float* __restrict__ hpre,
                       float* __restrict__ scal) {
  __shared__ float sW[1024];
  __shared__ float sx[64];
  __shared__ float red[8];
  int t = threadIdx.x;
  int blk = blockIdx.x;
#pragma unroll
  for (int i = 0; i < 4; ++i) sW[t + i * 256] = rootw[t + i * 256];
  if (t < 64) sx[t] = x[(size_t)blk * 64 + t];
  __syncthreads();
  int ln = t >> 6, h = t & 63;
  int n = blk * 4 + ln;
  float acc = conv1b[h];
#pragma unroll
  for (int f = 0; f < 16; ++f) acc += sx[ln * 16 + f] * sW[f * 64 + h];
  float dv = fmaxf(deg[n], 1.0f);
  float v = acc + agg[(size_t)n * 64 + h] / dv;
  v = fmaxf(v, 0.f);
  hpre[(size_t)n * 64 + h] = v;
  float s1 = v, s2 = v * v;
  for (int o = 32; o > 0; o >>= 1) { s1 += __shfl_down(s1, o); s2 += __shfl_down(s2, o); }
  if ((t & 63) == 0) { red[t >> 6] = s1; red[4 + (t >> 6)] = s2; }
  __syncthreads();
  if (t == 0) {
    atomicAdd(&scal[0], red[0] + red[1] + red[2] + red[3]);
    atomicAdd(&scal[1], red[4] + red[5] + red[6] + red[7]);
  }
}

// fold LN1 into gat_w:  gw2[i][j]=sH[i]*gatw[i][j], tb[j]=sum_i tH[i]*gatw[i][j]
__global__ void k_fold1(const float* __restrict__ scal, const float* __restrict__ n1w,
                        const float* __restrict__ n1b, const float* __restrict__ gatw,
                        float* __restrict__ gw2, float* __restrict__ tb) {
  __shared__ float sS[64], sT[64];
  int t = threadIdx.x;
  const float M = (float)N_NODES * 64.f;
  float mu = scal[0] / M;
  float var = fmaxf(scal[1] / M - mu * mu, 0.f);
  float inv = 1.f / (sqrtf(var) + LNEPS);
  sS[t] = inv * n1w[t];
  sT[t] = n1b[t] - mu * inv * n1w[t];
  __syncthreads();
  float acc = 0.f;
  for (int i = 0; i < 64; ++i) {
    float g = gatw[i * 64 + t];
    gw2[i * 64 + t] = sS[i] * g;
    acc += sT[i] * g;
  }
  tb[t] = acc;
}

// xh = hpre@gw2 + tb ; attention scalars
__global__ void k_gatlin(const float* __restrict__ hpre, const float* __restrict__ gw2,
                         const float* __restrict__ tb, const float* __restrict__ attS,
                         const float* __restrict__ attD, float* __restrict__ xh,
                         float* __restrict__ asrc, float* __restrict__ adst) {
  __shared__ float sW[4096];
  __shared__ float sh[256];
  __shared__ float sxh[256];
  int t = threadIdx.x;
  int blk = blockIdx.x;
#pragma unroll
  for (int i = 0; i < 16; ++i) sW[t + i * 256] = gw2[t + i * 256];
  sh[t] = hpre[(size_t)blk * 256 + t];
  __syncthreads();
  int ln = t >> 6, h = t & 63;
  float acc = tb[h];
  for (int i = 0; i < 64; ++i) acc += sh[ln * 64 + i] * sW[i * 64 + h];
  xh[(size_t)blk * 256 + t] = acc;
  sxh[t] = acc;
  __syncthreads();
  if (t < 32) {
    int ln2 = t >> 3, rem = t & 7;
    int hd = rem & 3;
    const float* av = (rem >> 2) ? attD : attS;
    float a = 0.f;
#pragma unroll
    for (int d = 0; d < 16; ++d) a += sxh[ln2 * 64 + hd * 16 + d] * av[hd * 16 + d];
    int n = blk * 4 + ln2;
    if (rem >> 2) adst[n * 4 + hd] = a; else asrc[n * 4 + hd] = a;
  }
}

__global__ void k_amax(const int* __restrict__ ei, const float* __restrict__ asrc,
                       const float* __restrict__ adst, unsigned* __restrict__ amax) {
  int i = blockIdx.x * 256 + threadIdx.x;
  if (i >= E_EDGES + N_NODES) return;
  int s, d;
  if (i < E_EDGES) { s = ei[i]; d = ei[E_EDGES + i]; } else { s = d = i - E_EDGES; }
#pragma unroll
  for (int hd = 0; hd < 4; ++hd) {
    float a = asrc[s * 4 + hd] + adst[d * 4 + hd];
    a = (a > 0.f) ? a : 0.2f * a;
    atomicMax(&amax[d * 4 + hd], fkey(a));
  }
}

__global__ void k_aexp(const int* __restrict__ ei, const float* __restrict__ asrc,
                       const float* __restrict__ adst, const unsigned* __restrict__ amax,
                       float* __restrict__ wexp, float* __restrict__ asum) {
  int i = blockIdx.x * 256 + threadIdx.x;
  if (i >= E_EDGES + N_NODES) return;
  int s, d;
  if (i < E_EDGES) { s = ei[i]; d = ei[E_EDGES + i]; } else { s = d = i - E_EDGES; }
#pragma unroll
  for (int hd = 0; hd < 4; ++hd) {
    float a = asrc[s * 4 + hd] + adst[d * 4 + hd];
    a = (a > 0.f) ? a : 0.2f * a;
    float w = expf(a - fdec(amax[d * 4 + hd]));
    wexp[(size_t)i * 4 + hd] = w;
    atomicAdd(&asum[d * 4 + hd], w);
  }
}

__global__ void k_gagg(const int* __restrict__ ei, const float* __restrict__ wexp,
                       const float* __restrict__ asum, const float* __restrict__ xh,
                       float* __restrict__ gout) {
  size_t j = (size_t)blockIdx.x * 256 + threadIdx.x;
  int i = (int)(j >> 6);
  int dim = (int)(j & 63);
  int hd = dim >> 4;
  int s, d;
  if (i < E_EDGES) { s = ei[i]; d = ei[E_EDGES + i]; } else { s = d = i - E_EDGES; }
  float c = wexp[(size_t)i * 4 + hd] / (asum[d * 4 + hd] + 1e-16f);
  atomicAdd(&gout[(size_t)d * 64 + dim], c * xh[(size_t)s * 64 + dim]);
}

__global__ void k_stat2(const float* __restrict__ gout, const float* __restrict__ gatb,
                        float* __restrict__ scal) {
  __shared__ float red[8];
  int t = threadIdx.x;
  size_t idx = (size_t)blockIdx.x * 256 + t;
  float v = fmaxf(gout[idx] + gatb[idx & 63], 0.f);
  float s1 = v, s2 = v * v;
  for (int o = 32; o > 0; o >>= 1) { s1 += __shfl_down(s1, o); s2 += __shfl_down(s2, o); }
  if ((t & 63) == 0) { red[t >> 6] = s1; red[4 + (t >> 6)] = s2; }
  __syncthreads();
  if (t == 0) {
    atomicAdd(&scal[2], red[0] + red[1] + red[2] + red[3]);
    atomicAdd(&scal[3], red[4] + red[5] + red[6] + red[7]);
  }
}

// fold LN2 + pool + linear head:  wl[h]=inv*n2w*linw ; wl[64]=const term
__global__ void k_fold2(const float* __restrict__ scal, const float* __restrict__ n2w,
                        const float* __restrict__ n2b, const float* __restrict__ linw,
                        const float* __restrict__ linb, float* __restrict__ wl) {
  int t = threadIdx.x;
  const float M = (float)N_NODES * 64.f;
  float mu = scal[2] / M;
  float var = fmaxf(scal[3] / M - mu * mu, 0.f);
  float inv = 1.f / (sqrtf(var) + LNEPS);
  float w = inv * n2w[t] * linw[t];
  float p = (n2b[t] - mu * inv * n2w[t]) * linw[t];
  wl[t] = w;
  for (int o = 32; o > 0; o >>= 1) p += __shfl_down(p, o);
  if (t == 0) wl[64] = p + linb[0];
}

__global__ void k_pool(const float* __restrict__ gout, const float* __restrict__ gatb,
                       const float* __restrict__ wl, const int* __restrict__ batch,
                       float* __restrict__ pooled, float* __restrict__ cnt) {
  int t = threadIdx.x;
  int wv = t >> 6, lane = t & 63;
  int n = blockIdx.x * 4 + wv;
  float v = fmaxf(gout[(size_t)n * 64 + lane] + gatb[lane], 0.f) * wl[lane];
  for (int o = 32; o > 0; o >>= 1) v += __shfl_down(v, o);
  if (lane == 0) {
    int g = batch[n];
    atomicAdd(&pooled[g], v);
    atomicAdd(&cnt[g], 1.f);
  }
}

__global__ void k_out(const float* __restrict__ pooled, const float* __restrict__ cnt,
                      const float* __restrict__ wl, float* __restrict__ out) {
  int g = threadIdx.x;
  out[g] = pooled[g] / fmaxf(cnt[g], 1.f) + wl[64];
}

// ---------------- workspace layout (bytes, all 64B aligned) ----------------
#define OFF_AGG   0UL
#define OFF_GOUT  12800000UL
#define OFF_DEG   25600000UL
#define OFF_AMAX  25800000UL
#define OFF_ASUM  26600000UL
#define OFF_POOL  27400000UL
#define OFF_CNT   27400256UL
#define OFF_SCAL  27400512UL
#define ZBYTES    27400768UL
#define OFF_TT    27400768UL
#define OFF_W1T   29514304UL
#define OFF_GW2   29547072UL
#define OFF_TB    29563456UL
#define OFF_WL    29563712UL
#define OFF_HPRE  29564224UL
#define OFF_XH    42364224UL
#define OFF_ASRC  55164224UL
#define OFF_ADST  55964224UL
#define OFF_WEXP  56764224UL
#define WS_NEED   62364224UL

extern "C" void kernel_launch(void* const* d_in, const int* in_sizes, int n_in,
                              void* d_out, int out_size, void* d_ws, size_t ws_size,
                              hipStream_t stream) {
  const float* x = (const float*)d_in[0];
  const int* ei = (const int*)d_in[1];
  const float* ea = (const float*)d_in[2];
  const int* batch = (const int*)d_in[3];
  const float* w1 = (const float*)d_in[4];
  const float* b1 = (const float*)d_in[5];
  const float* w2 = (const float*)d_in[6];
  const float* b2 = (const float*)d_in[7];
  const float* rootw = (const float*)d_in[8];
  const float* conv1b = (const float*)d_in[9];
  const float* n1w = (const float*)d_in[10];
  const float* n1b = (const float*)d_in[11];
  const float* gatw = (const float*)d_in[12];
  const float* attS = (const float*)d_in[13];
  const float* attD = (const float*)d_in[14];
  const float* gatb = (const float*)d_in[15];
  const float* n2w = (const float*)d_in[16];
  const float* n2b = (const float*)d_in[17];
  const float* linw = (const float*)d_in[18];
  const float* linb = (const float*)d_in[19];

  if (ws_size < WS_NEED) return;
  char* ws = (char*)d_ws;
  float* agg   = (float*)(ws + OFF_AGG);
  float* gout  = (float*)(ws + OFF_GOUT);
  float* deg   = (float*)(ws + OFF_DEG);
  unsigned* amax = (unsigned*)(ws + OFF_AMAX);
  float* asum  = (float*)(ws + OFF_ASUM);
  float* pooled = (float*)(ws + OFF_POOL);
  float* cnt   = (float*)(ws + OFF_CNT);
  float* scal  = (float*)(ws + OFF_SCAL);
  __bf16* Tt   = (__bf16*)(ws + OFF_TT);
  float* W1t   = (float*)(ws + OFF_W1T);
  float* gw2   = (float*)(ws + OFF_GW2);
  float* tb    = (float*)(ws + OFF_TB);
  float* wl    = (float*)(ws + OFF_WL);
  float* hpre  = (float*)(ws + OFF_HPRE);
  float* xh    = (float*)(ws + OFF_XH);
  float* asrc  = (float*)(ws + OFF_ASRC);
  float* adst  = (float*)(ws + OFF_ADST);
  float* wexp  = (float*)(ws + OFF_WEXP);

  hipMemsetAsync(ws, 0, ZBYTES, stream);

  k_prep<<<4160, 256, 0, stream>>>(w2, b2, w1, Tt, W1t);
  k_deg<<<(E_EDGES + 255) / 256, 256, 0, stream>>>(ei, deg);
  k_nnconv<<<(E_EDGES + 255) / 256, 256, 0, stream>>>(x, ei, ea, W1t, b1, Tt, agg);
  k_root<<<N_NODES / 4, 256, 0, stream>>>(x, rootw, conv1b, agg, deg, hpre, scal);
  k_fold1<<<1, 64, 0, stream>>>(scal, n1w, n1b, gatw, gw2, tb);
  k_gatlin<<<N_NODES / 4, 256, 0, stream>>>(hpre, gw2, tb, attS, attD, xh, asrc, adst);
  k_amax<<<(E_EDGES + N_NODES + 255) / 256, 256, 0, stream>>>(ei, asrc, adst, amax);
  k_aexp<<<(E_EDGES + N_NODES + 255) / 256, 256, 0, stream>>>(ei, asrc, adst, amax, wexp, asum);
  k_gagg<<<(E_EDGES + N_NODES) / 4, 256, 0, stream>>>(ei, wexp, asum, xh, gout);
  k_stat2<<<N_NODES * 64 / 256, 256, 0, stream>>>(gout, gatb, scal);
  k_fold2<<<1, 64, 0, stream>>>(scal, n2w, n2b, linw, linb, wl);
  k_pool<<<N_NODES / 4, 256, 0, stream>>>(gout, gatb, wl, batch, pooled, cnt);
  k_out<<<1, 64, 0, stream>>>(pooled, cnt, wl, (float*)d_out);
}

// Round 2
// 2045.620 us; speedup vs baseline: 1.1597x; 1.1597x over previous
//
#include <hip/hip_runtime.h>
#include <hip/hip_bf16.h>

#define N_NODES 50000
#define E_EDGES 300000
#define NGRAPH 64
#define KTOT 16512   // 1024*16 kf + 128 pad chunk (first 16 carry b2)
#define KC 128
#define NCHUNK 129
#define LNEPS 1e-5f
#define NBLK_N 196   // ceil(50000/256)

typedef __bf16 bf16x8 __attribute__((ext_vector_type(8)));
typedef float floatx4 __attribute__((ext_vector_type(4)));

__device__ __forceinline__ void async_load16(const void* g, void* l) {
  __builtin_amdgcn_global_load_lds(
      (__attribute__((address_space(1))) void*)g,
      (__attribute__((address_space(3))) void*)l, 16, 0, 0);
}

// pack two f32 -> bf16x2 with round-half-up: 2 adds + 1 v_perm
__device__ __forceinline__ unsigned pkbf(float a, float b) {
  unsigned ua = __float_as_uint(a) + 0x8000u;
  unsigned ub = __float_as_uint(b) + 0x8000u;
  return __builtin_amdgcn_perm(ub, ua, 0x07060302u);
}

// ---------------- prep: Tt[h][kf] bf16 via LDS tile transpose ----------------
__global__ void k_prep(const float* __restrict__ w2, const float* __restrict__ b2,
                       __bf16* __restrict__ Tt) {
  __shared__ float tile[64][65];
  int t = threadIdx.x;
  int kf0 = blockIdx.x * 64;      // 258 blocks
  int r4 = t >> 6;
  int cc = t & 63;
#pragma unroll
  for (int p = 0; p < 16; ++p) {
    int row = p * 4 + r4;
    int kf = kf0 + row;
    float v = 0.f;
    if (kf < 16384) {
      int k = kf >> 4, f = kf & 15;
      v = w2[k * 1024 + f * 64 + cc];      // 64 consecutive floats per row: coalesced
    } else if (kf < 16400) {
      v = b2[(kf - 16384) * 64 + cc];
    }
    tile[row][cc] = v;
  }
  __syncthreads();
#pragma unroll
  for (int p = 0; p < 16; ++p) {
    int h = p * 4 + r4;
    Tt[(size_t)h * KTOT + kf0 + cc] = (__bf16)tile[cc][h];
  }
}

__global__ void k_prepw(const float* __restrict__ w1, float* __restrict__ W1t) {
  int i = blockIdx.x * 256 + threadIdx.x;
  if (i < 8192) { int k = i >> 3, j = i & 7; W1t[i] = w1[j * 1024 + k]; }
}

// ---------------- CSR build ----------------
__global__ void k_cnt(const int* __restrict__ ei, int* __restrict__ degI) {
  int e = blockIdx.x * 256 + threadIdx.x;
  if (e < E_EDGES) atomicAdd(&degI[ei[E_EDGES + e]], 1);
}

__global__ void k_scanA(const int* __restrict__ degI, int* __restrict__ bsum) {
  __shared__ int sm[256];
  int t = threadIdx.x;
  int i = blockIdx.x * 256 + t;
  sm[t] = (i < N_NODES) ? degI[i] : 0;
  __syncthreads();
  for (int off = 128; off > 0; off >>= 1) {
    if (t < off) sm[t] += sm[t + off];
    __syncthreads();
  }
  if (t == 0) bsum[blockIdx.x] = sm[0];
}

__global__ void k_scanB(const int* __restrict__ bsum, int* __restrict__ bpre) {
  __shared__ int s[256];
  int t = threadIdx.x;
  int v = (t < NBLK_N) ? bsum[t] : 0;
  s[t] = v;
  __syncthreads();
  for (int off = 1; off < 256; off <<= 1) {
    int add = (t >= off) ? s[t - off] : 0;
    __syncthreads();
    s[t] += add;
    __syncthreads();
  }
  if (t < NBLK_N) bpre[t] = s[t] - v;
}

__global__ void k_scanC(const int* __restrict__ degI, const int* __restrict__ bpre,
                        int* __restrict__ rowptr, int* __restrict__ cursor) {
  __shared__ int s[256];
  int t = threadIdx.x;
  int i = blockIdx.x * 256 + t;
  int d = (i < N_NODES) ? degI[i] : 0;
  s[t] = d;
  __syncthreads();
  for (int off = 1; off < 256; off <<= 1) {
    int add = (t >= off) ? s[t - off] : 0;
    __syncthreads();
    s[t] += add;
    __syncthreads();
  }
  int r = bpre[blockIdx.x] + s[t] - d;   // exclusive
  if (i < N_NODES) {
    rowptr[i] = r;
    cursor[i] = r;
    if (i == N_NODES - 1) rowptr[N_NODES] = r + d;
  }
}

__global__ void k_scatter(const int* __restrict__ ei, int* __restrict__ cursor,
                          int* __restrict__ colsrc) {
  int e = blockIdx.x * 256 + threadIdx.x;
  if (e < E_EDGES) {
    int s = ei[e], d = ei[E_EDGES + e];
    int pos = atomicAdd(&cursor[d], 1);
    colsrc[pos] = s;
  }
}

// ---------------- NNConv fused MFMA GEMM ----------------
__global__ __launch_bounds__(256, 3)
void k_nnconv(const float* __restrict__ x, const int* __restrict__ ei,
              const float* __restrict__ ea, const float* __restrict__ W1t,
              const float* __restrict__ b1, const __bf16* __restrict__ Tt,
              float* __restrict__ agg) {
  __shared__ __align__(16) __bf16 sB[2][64 * KC];  // 32 KB
  __shared__ int sSrc[256];
  __shared__ int sDst[256];

  const int tid = threadIdx.x;
  const int wv = tid >> 6;
  const int lane = tid & 63;
  const int l15 = lane & 15;
  const int quad = lane >> 4;
  const int base = blockIdx.x * 256;

  int e = base + tid;
  bool valid = e < E_EDGES;
  sSrc[tid] = valid ? ei[e] : 0;
  sDst[tid] = valid ? ei[E_EDGES + e] : -1;

  float eaw[8];
  {
    const float4* p = (const float4*)(ea + (size_t)(valid ? e : 0) * 8);
    float4 a0 = p[0], a1 = p[1];
    eaw[0] = a0.x; eaw[1] = a0.y; eaw[2] = a0.z; eaw[3] = a0.w;
    eaw[4] = a1.x; eaw[5] = a1.y; eaw[6] = a1.z; eaw[7] = a1.w;
  }
  __syncthreads();

  const int f0 = (quad & 1) * 8;
  float xf[4][8];
#pragma unroll
  for (int mb = 0; mb < 4; ++mb) {
    int el = wv * 64 + mb * 16 + l15;
    const float4* px = (const float4*)(x + (size_t)sSrc[el] * 16 + f0);
    float4 v0 = px[0], v1 = px[1];
    xf[mb][0] = v0.x; xf[mb][1] = v0.y; xf[mb][2] = v0.z; xf[mb][3] = v0.w;
    xf[mb][4] = v1.x; xf[mb][5] = v1.y; xf[mb][6] = v1.z; xf[mb][7] = v1.w;
  }

  auto stageB = [&](int buf, int c) {
#pragma unroll
    for (int it = 0; it < 4; ++it) {
      int q = it * 256 + tid;
      int h = q >> 4, sc = q & 15;
      int cc = sc ^ (h & 15);
      async_load16(Tt + (size_t)h * KTOT + c * KC + cc * 8, &sB[buf][q * 8]);
    }
  };

  float rr[8];
  auto calcR = [&](int c) {
    if (c < 128) {   // uniform branch
#pragma unroll
      for (int kk = 0; kk < 8; ++kk) {
        int k = c * 8 + kk;
        const float4* w = (const float4*)(W1t + k * 8);  // uniform addr -> s_load
        float4 w0 = w[0], w1v = w[1];
        float v = b1[k];
        v += eaw[0] * w0.x + eaw[1] * w0.y + eaw[2] * w0.z + eaw[3] * w0.w;
        v += eaw[4] * w1v.x + eaw[5] * w1v.y + eaw[6] * w1v.z + eaw[7] * w1v.w;
        v = fmaxf(v, 0.f);
        rr[kk] = valid ? v : 0.f;
      }
    } else {
#pragma unroll
      for (int kk = 0; kk < 8; ++kk)
        rr[kk] = (valid && (c * 8 + kk) == 1024) ? 1.f : 0.f;  // b2 row
    }
  };

  floatx4 acc[4][4];
#pragma unroll
  for (int mb = 0; mb < 4; ++mb)
#pragma unroll
    for (int nb = 0; nb < 4; ++nb) acc[mb][nb] = floatx4{0.f, 0.f, 0.f, 0.f};

  stageB(0, 0);
  calcR(0);
  int buf = 0;
  for (int c = 0; c < NCHUNK; ++c) {
    __syncthreads();
    if (c + 1 < NCHUNK) stageB(buf ^ 1, c + 1);
#pragma unroll
    for (int ks = 0; ks < 4; ++ks) {
      bf16x8 bfr[4];
#pragma unroll
      for (int nb = 0; nb < 4; ++nb) {
        int h = nb * 16 + l15;
        int cc = (ks * 4 + quad) ^ l15;
        bfr[nb] = *(const bf16x8*)&sB[buf][h * KC + cc * 8];
      }
#pragma unroll
      for (int mb = 0; mb < 4; ++mb) {
        float rv0 = __shfl(rr[2 * ks], mb * 16 + l15);
        float rv1 = __shfl(rr[2 * ks + 1], mb * 16 + l15);
        float rv = (quad & 2) ? rv1 : rv0;
        union { unsigned u[4]; bf16x8 v; } A;
#pragma unroll
        for (int jj = 0; jj < 4; ++jj)
          A.u[jj] = pkbf(rv * xf[mb][2 * jj], rv * xf[mb][2 * jj + 1]);
#pragma unroll
        for (int nb = 0; nb < 4; ++nb)
          acc[mb][nb] = __builtin_amdgcn_mfma_f32_16x16x32_bf16(A.v, bfr[nb], acc[mb][nb], 0, 0, 0);
      }
    }
    if (c + 1 < NCHUNK) calcR(c + 1);  // next chunk's r (wave-synchronous: all shfls above done)
    buf ^= 1;
  }

  // epilogue: scatter msg to agg[dst]  (C layout: row=quad*4+reg, col=l15)
#pragma unroll
  for (int mb = 0; mb < 4; ++mb) {
    int el = wv * 64 + mb * 16 + quad * 4;
#pragma unroll
    for (int reg = 0; reg < 4; ++reg) {
      int dd = sDst[el + reg];
      if (dd >= 0) {
#pragma unroll
        for (int nb = 0; nb < 4; ++nb)
          atomicAdd(&agg[(size_t)dd * 64 + nb * 16 + l15], acc[mb][nb][reg]);
      }
    }
  }
}

// ---------------- h = relu(x@rootw + agg/deg + b); LN1 stats ----------------
__global__ void k_root(const float* __restrict__ x, const float* __restrict__ rootw,
                       const float* __restrict__ conv1b, const float* __restrict__ agg,
                       const int* __restrict__ degI, float* __restrict__ hpre,
                       float* __restrict__ scal) {
  __shared__ float sW[1024];
  __shared__ float sx[64];
  __shared__ float red[8];
  int t = threadIdx.x;
  int blk = blockIdx.x;
#pragma unroll
  for (int i = 0; i < 4; ++i) sW[t + i * 256] = rootw[t + i * 256];
  if (t < 64) sx[t] = x[(size_t)blk * 64 + t];
  __syncthreads();
  int ln = t >> 6, h = t & 63;
  int n = blk * 4 + ln;
  float acc = conv1b[h];
#pragma unroll
  for (int f = 0; f < 16; ++f) acc += sx[ln * 16 + f] * sW[f * 64 + h];
  float dv = fmaxf((float)degI[n], 1.0f);
  float v = acc + agg[(size_t)n * 64 + h] / dv;
  v = fmaxf(v, 0.f);
  hpre[(size_t)n * 64 + h] = v;
  float s1 = v, s2 = v * v;
  for (int o = 32; o > 0; o >>= 1) { s1 += __shfl_down(s1, o); s2 += __shfl_down(s2, o); }
  if ((t & 63) == 0) { red[t >> 6] = s1; red[4 + (t >> 6)] = s2; }
  __syncthreads();
  if (t == 0) {
    atomicAdd(&scal[0], red[0] + red[1] + red[2] + red[3]);
    atomicAdd(&scal[1], red[4] + red[5] + red[6] + red[7]);
  }
}

// fold LN1 into gat_w
__global__ void k_fold1(const float* __restrict__ scal, const float* __restrict__ n1w,
                        const float* __restrict__ n1b, const float* __restrict__ gatw,
                        float* __restrict__ gw2, float* __restrict__ tb) {
  __shared__ float sS[64], sT[64];
  int t = threadIdx.x;
  const float M = (float)N_NODES * 64.f;
  float mu = scal[0] / M;
  float var = fmaxf(scal[1] / M - mu * mu, 0.f);
  float inv = 1.f / (sqrtf(var) + LNEPS);
  sS[t] = inv * n1w[t];
  sT[t] = n1b[t] - mu * inv * n1w[t];
  __syncthreads();
  float acc = 0.f;
  for (int i = 0; i < 64; ++i) {
    float g = gatw[i * 64 + t];
    gw2[i * 64 + t] = sS[i] * g;
    acc += sT[i] * g;
  }
  tb[t] = acc;
}

// xh = hpre@gw2 + tb ; attention scalars
__global__ void k_gatlin(const float* __restrict__ hpre, const float* __restrict__ gw2,
                         const float* __restrict__ tb, const float* __restrict__ attS,
                         const float* __restrict__ attD, float* __restrict__ xh,
                         float* __restrict__ asrc, float* __restrict__ adst) {
  __shared__ float sW[4096];
  __shared__ float sh[256];
  __shared__ float sxh[256];
  int t = threadIdx.x;
  int blk = blockIdx.x;
#pragma unroll
  for (int i = 0; i < 16; ++i) sW[t + i * 256] = gw2[t + i * 256];
  sh[t] = hpre[(size_t)blk * 256 + t];
  __syncthreads();
  int ln = t >> 6, h = t & 63;
  float acc = tb[h];
  for (int i = 0; i < 64; ++i) acc += sh[ln * 64 + i] * sW[i * 64 + h];
  xh[(size_t)blk * 256 + t] = acc;
  sxh[t] = acc;
  __syncthreads();
  if (t < 32) {
    int ln2 = t >> 3, rem = t & 7;
    int hd = rem & 3;
    const float* av = (rem >> 2) ? attD : attS;
    float a = 0.f;
#pragma unroll
    for (int d = 0; d < 16; ++d) a += sxh[ln2 * 64 + hd * 16 + d] * av[hd * 16 + d];
    int n = blk * 4 + ln2;
    if (rem >> 2) adst[n * 4 + hd] = a; else asrc[n * 4 + hd] = a;
  }
}

// ---------------- GAT: CSR gather, online softmax, fused relu+LN2 stats ----------------
__global__ void k_gat(const int* __restrict__ rowptr, const int* __restrict__ colsrc,
                      const float* __restrict__ xh, const float* __restrict__ asrc,
                      const float* __restrict__ adst, const float* __restrict__ gatb,
                      float* __restrict__ act, float* __restrict__ scal) {
  __shared__ float sP[4][256];
  __shared__ int sS[4][64];
  __shared__ float sRed[8];
  int t = threadIdx.x;
  int wv = t >> 6, lane = t & 63;
  int n = blockIdx.x * 4 + wv;
  int start = rowptr[n], end = rowptr[n + 1];
  int deg = end - start;
  int myhd = lane >> 4;
  float ad[4];
#pragma unroll
  for (int hd = 0; hd < 4; ++hd) ad[hd] = adst[n * 4 + hd];
  float m[4] = {-1e30f, -1e30f, -1e30f, -1e30f};
  float l[4] = {0.f, 0.f, 0.f, 0.f};
  float O = 0.f;
  int items = deg + 1;  // + self loop
  for (int t0 = 0; t0 < items; t0 += 64) {
    int cnt = min(64, items - t0);
    int idx = t0 + lane;
    bool has = lane < cnt;
    int s = n;
    if (has && idx < deg) s = colsrc[start + idx];
    float a[4];
#pragma unroll
    for (int hd = 0; hd < 4; ++hd) {
      float av = has ? (asrc[s * 4 + hd] + ad[hd]) : -1e30f;
      a[hd] = (av > 0.f) ? av : 0.2f * av;  // leaky relu 0.2
    }
    float tm[4];
#pragma unroll
    for (int hd = 0; hd < 4; ++hd) tm[hd] = a[hd];
#pragma unroll
    for (int off = 32; off > 0; off >>= 1)
#pragma unroll
      for (int hd = 0; hd < 4; ++hd) tm[hd] = fmaxf(tm[hd], __shfl_xor(tm[hd], off));
    float p[4];
#pragma unroll
    for (int hd = 0; hd < 4; ++hd) {
      float mn = fmaxf(m[hd], tm[hd]);
      float sc = __expf(m[hd] - mn);
      l[hd] *= sc;
      if (hd == myhd) O *= sc;
      m[hd] = mn;
      p[hd] = has ? __expf(a[hd] - mn) : 0.f;
    }
    float ts[4];
#pragma unroll
    for (int hd = 0; hd < 4; ++hd) ts[hd] = p[hd];
#pragma unroll
    for (int off = 32; off > 0; off >>= 1)
#pragma unroll
      for (int hd = 0; hd < 4; ++hd) ts[hd] += __shfl_xor(ts[hd], off);
#pragma unroll
    for (int hd = 0; hd < 4; ++hd) l[hd] += ts[hd];
    sS[wv][lane] = s;
#pragma unroll
    for (int hd = 0; hd < 4; ++hd) sP[wv][lane * 4 + hd] = p[hd];
    // wave-private LDS region: program order suffices, no barrier
    for (int e2 = 0; e2 < cnt; ++e2) {
      int ss = sS[wv][e2];
      float pp = sP[wv][e2 * 4 + myhd];
      O = fmaf(pp, xh[(size_t)ss * 64 + lane], O);
    }
  }
  float lmy = (myhd & 2) ? ((myhd & 1) ? l[3] : l[2]) : ((myhd & 1) ? l[1] : l[0]);
  float outv = O / (lmy + 1e-16f);
  float v = fmaxf(outv + gatb[lane], 0.f);
  act[(size_t)n * 64 + lane] = v;
  float s1 = v, s2 = v * v;
#pragma unroll
  for (int off = 32; off > 0; off >>= 1) { s1 += __shfl_down(s1, off); s2 += __shfl_down(s2, off); }
  if (lane == 0) { sRed[wv] = s1; sRed[4 + wv] = s2; }
  __syncthreads();
  if (t == 0) {
    atomicAdd(&scal[2], sRed[0] + sRed[1] + sRed[2] + sRed[3]);
    atomicAdd(&scal[3], sRed[4] + sRed[5] + sRed[6] + sRed[7]);
  }
}

// fold LN2 + pool + linear head
__global__ void k_fold2(const float* __restrict__ scal, const float* __restrict__ n2w,
                        const float* __restrict__ n2b, const float* __restrict__ linw,
                        const float* __restrict__ linb, float* __restrict__ wl) {
  int t = threadIdx.x;
  const float M = (float)N_NODES * 64.f;
  float mu = scal[2] / M;
  float var = fmaxf(scal[3] / M - mu * mu, 0.f);
  float inv = 1.f / (sqrtf(var) + LNEPS);
  float w = inv * n2w[t] * linw[t];
  float p = (n2b[t] - mu * inv * n2w[t]) * linw[t];
  wl[t] = w;
  for (int o = 32; o > 0; o >>= 1) p += __shfl_down(p, o);
  if (t == 0) wl[64] = p + linb[0];
}

__global__ void k_pool(const float* __restrict__ act, const float* __restrict__ wl,
                       const int* __restrict__ batch, float* __restrict__ pooled,
                       float* __restrict__ cnt) {
  int t = threadIdx.x;
  int wv = t >> 6, lane = t & 63;
  int n = blockIdx.x * 4 + wv;
  float v = act[(size_t)n * 64 + lane] * wl[lane];
  for (int o = 32; o > 0; o >>= 1) v += __shfl_down(v, o);
  if (lane == 0) {
    int g = batch[n];
    atomicAdd(&pooled[g], v);
    atomicAdd(&cnt[g], 1.f);
  }
}

__global__ void k_out(const float* __restrict__ pooled, const float* __restrict__ cnt,
                      const float* __restrict__ wl, float* __restrict__ out) {
  int g = threadIdx.x;
  out[g] = pooled[g] / fmaxf(cnt[g], 1.f) + wl[64];
}

// ---------------- workspace layout (bytes) ----------------
#define OFF_AGG     0UL
#define OFF_DEGI    12800000UL
#define OFF_SCAL    13000000UL
#define OFF_POOL    13000064UL
#define OFF_CNT     13000320UL
#define ZBYTES      13000576UL
#define OFF_ROWPTR  13000576UL
#define OFF_CURSOR  13200640UL
#define OFF_BSUM    13400640UL
#define OFF_BPRE    13401472UL
#define OFF_COLSRC  13402304UL
#define OFF_TT      14602304UL
#define OFF_W1T     16715840UL
#define OFF_GW2     16748608UL
#define OFF_TB      16764992UL
#define OFF_WL      16765248UL
#define OFF_ASRC    16765568UL
#define OFF_ADST    17565568UL
#define OFF_HPRE    18365568UL
#define OFF_XH      31165568UL
#define OFF_ACT     43965568UL
#define WS_NEED     56765568UL

extern "C" void kernel_launch(void* const* d_in, const int* in_sizes, int n_in,
                              void* d_out, int out_size, void* d_ws, size_t ws_size,
                              hipStream_t stream) {
  const float* x = (const float*)d_in[0];
  const int* ei = (const int*)d_in[1];
  const float* ea = (const float*)d_in[2];
  const int* batch = (const int*)d_in[3];
  const float* w1 = (const float*)d_in[4];
  const float* b1 = (const float*)d_in[5];
  const float* w2 = (const float*)d_in[6];
  const float* b2 = (const float*)d_in[7];
  const float* rootw = (const float*)d_in[8];
  const float* conv1b = (const float*)d_in[9];
  const float* n1w = (const float*)d_in[10];
  const float* n1b = (const float*)d_in[11];
  const float* gatw = (const float*)d_in[12];
  const float* attS = (const float*)d_in[13];
  const float* attD = (const float*)d_in[14];
  const float* gatb = (const float*)d_in[15];
  const float* n2w = (const float*)d_in[16];
  const float* n2b = (const float*)d_in[17];
  const float* linw = (const float*)d_in[18];
  const float* linb = (const float*)d_in[19];

  if (ws_size < WS_NEED) return;
  char* ws = (char*)d_ws;
  float* agg    = (float*)(ws + OFF_AGG);
  int* degI     = (int*)(ws + OFF_DEGI);
  float* scal   = (float*)(ws + OFF_SCAL);
  float* pooled = (float*)(ws + OFF_POOL);
  float* cnt    = (float*)(ws + OFF_CNT);
  int* rowptr   = (int*)(ws + OFF_ROWPTR);
  int* cursor   = (int*)(ws + OFF_CURSOR);
  int* bsum     = (int*)(ws + OFF_BSUM);
  int* bpre     = (int*)(ws + OFF_BPRE);
  int* colsrc   = (int*)(ws + OFF_COLSRC);
  __bf16* Tt    = (__bf16*)(ws + OFF_TT);
  float* W1t    = (float*)(ws + OFF_W1T);
  float* gw2    = (float*)(ws + OFF_GW2);
  float* tb     = (float*)(ws + OFF_TB);
  float* wl     = (float*)(ws + OFF_WL);
  float* asrc   = (float*)(ws + OFF_ASRC);
  float* adst   = (float*)(ws + OFF_ADST);
  float* hpre   = (float*)(ws + OFF_HPRE);
  float* xh     = (float*)(ws + OFF_XH);
  float* act    = (float*)(ws + OFF_ACT);

  hipMemsetAsync(ws, 0, ZBYTES, stream);

  k_prep<<<258, 256, 0, stream>>>(w2, b2, Tt);
  k_prepw<<<32, 256, 0, stream>>>(w1, W1t);
  k_cnt<<<(E_EDGES + 255) / 256, 256, 0, stream>>>(ei, degI);
  k_scanA<<<NBLK_N, 256, 0, stream>>>(degI, bsum);
  k_scanB<<<1, 256, 0, stream>>>(bsum, bpre);
  k_scanC<<<NBLK_N, 256, 0, stream>>>(degI, bpre, rowptr, cursor);
  k_scatter<<<(E_EDGES + 255) / 256, 256, 0, stream>>>(ei, cursor, colsrc);
  k_nnconv<<<(E_EDGES + 255) / 256, 256, 0, stream>>>(x, ei, ea, W1t, b1, Tt, agg);
  k_root<<<N_NODES / 4, 256, 0, stream>>>(x, rootw, conv1b, agg, degI, hpre, scal);
  k_fold1<<<1, 64, 0, stream>>>(scal, n1w, n1b, gatw, gw2, tb);
  k_gatlin<<<N_NODES / 4, 256, 0, stream>>>(hpre, gw2, tb, attS, attD, xh, asrc, adst);
  k_gat<<<N_NODES / 4, 256, 0, stream>>>(rowptr, colsrc, xh, asrc, adst, gatb, act, scal);
  k_fold2<<<1, 64, 0, stream>>>(scal, n2w, n2b, linw, linb, wl);
  k_pool<<<N_NODES / 4, 256, 0, stream>>>(act, wl, batch, pooled, cnt);
  k_out<<<1, 64, 0, stream>>>(pooled, cnt, wl, (float*)d_out);
}